// Round 9
// baseline (389.784 us; speedup 1.0000x reference)
//
#include <hip/hip_runtime.h>
#include <hip/hip_fp16.h>

// Topology encoder: 2-layer GCN (N=100k nodes, E=3.2M edges) + max/mean pool
// over B=64 graphs + 2-layer MLP. fp32 in/out; node features stored fp16 in
// TWO PLANES of N x 16 (3.2 MB each -> L2-resident per XCD during gathers).
//
// CSR-by-dst built per call with ZERO global atomics:
//   k_histB  : per-block LDS bucket histogram -> bcnt[bucket][block]
//   k_rowscan: per-bucket exclusive scan of bcnt row -> private offsets + tot
//   k_bscan  : single-block scan of bucket totals -> bstart
//   k_bin    : LDS cursors (private per block) -> packed, contiguous runs
//   k_place2 : per-bucket LDS degree count + scan -> rowptr, dinv, col
// Each GCN layer = 2 gather passes (one per feature plane), fused with
// bias+ReLU+pooling (wave-reduced atomics).

#define F 32
#define POOLD 64
#define BKT 512           // nodes per bucket (log2 = 9); place2 blockDim == BKT
#define BKTL2 9
#define EPB 8192          // edges per k_histB/k_bin block
#define MAXBUCK 256       // supports N <= 131072

typedef __attribute__((ext_vector_type(8))) _Float16 half8;

// ---- per-block LDS bucket histogram; direct store to bcnt[b][blk] ----
__global__ void k_histB(const int* __restrict__ ei, int* __restrict__ bcnt,
                        int e, int nbuck, int nblk) {
    __shared__ int h[MAXBUCK];
    for (int b = threadIdx.x; b < nbuck; b += 256) h[b] = 0;
    __syncthreads();
    int base = blockIdx.x * EPB;
#pragma unroll
    for (int k = 0; k < EPB / 1024; ++k) {
        int i = base + (k * 256 + threadIdx.x) * 4;
        if (i + 4 <= e) {
            int4 d4 = *reinterpret_cast<const int4*>(ei + e + i);
            atomicAdd(&h[d4.x >> BKTL2], 1);
            atomicAdd(&h[d4.y >> BKTL2], 1);
            atomicAdd(&h[d4.z >> BKTL2], 1);
            atomicAdd(&h[d4.w >> BKTL2], 1);
        } else {
            for (int j = i; j < e && j < i + 4; ++j)
                atomicAdd(&h[ei[e + j] >> BKTL2], 1);
        }
    }
    __syncthreads();
    for (int b = threadIdx.x; b < nbuck; b += 256)
        bcnt[b * nblk + blockIdx.x] = h[b];
}

// ---- per bucket: exclusive scan of bcnt row (in place) + row total ----
__global__ void k_rowscan(int* __restrict__ bcnt, int* __restrict__ tot, int nblk) {
    __shared__ int lds[256];
    int* row = bcnt + (size_t)blockIdx.x * nblk;
    int t = threadIdx.x;
    int running = 0;
    for (int chunk = 0; chunk < nblk; chunk += 256) {
        int idx = chunk + t;
        int v = (idx < nblk) ? row[idx] : 0;
        lds[t] = v;
        __syncthreads();
        int val = v;
        for (int off = 1; off < 256; off <<= 1) {
            int other = (t >= off) ? lds[t - off] : 0;
            __syncthreads();
            val += other;
            lds[t] = val;
            __syncthreads();
        }
        if (idx < nblk) row[idx] = running + val - v;  // exclusive
        running += lds[255];
        __syncthreads();
    }
    if (t == 0) tot[blockIdx.x] = running;
}

// ---- single block: scan bucket totals -> bstart (nbuck <= 256) ----
__global__ void k_bscan(const int* __restrict__ tot, int* __restrict__ bstart,
                        int nbuck, int e) {
    __shared__ int lds[256];
    int t = threadIdx.x;
    int v = (t < nbuck) ? tot[t] : 0;
    lds[t] = v;
    __syncthreads();
    int val = v;
    for (int off = 1; off < 256; off <<= 1) {
        int other = (t >= off) ? lds[t - off] : 0;
        __syncthreads();
        val += other;
        lds[t] = val;
        __syncthreads();
    }
    if (t < nbuck) bstart[t] = val - v;  // exclusive
    if (t == 0) bstart[nbuck] = e;
}

// ---- partition edges into private per-(bucket,block) runs; LDS cursors ----
__global__ void k_bin(const int* __restrict__ ei, const int* __restrict__ bstart,
                      const int* __restrict__ bcnt, int* __restrict__ packed,
                      int e, int nbuck, int nblk) {
    __shared__ int cur[MAXBUCK];
    for (int b = threadIdx.x; b < nbuck; b += 256)
        cur[b] = bstart[b] + bcnt[b * nblk + blockIdx.x];
    __syncthreads();
    int base = blockIdx.x * EPB;
#pragma unroll
    for (int k = 0; k < EPB / 1024; ++k) {
        int i = base + (k * 256 + threadIdx.x) * 4;
        if (i + 4 <= e) {
            int4 s4 = *reinterpret_cast<const int4*>(ei + i);
            int4 d4 = *reinterpret_cast<const int4*>(ei + e + i);
            int p0 = atomicAdd(&cur[d4.x >> BKTL2], 1);
            int p1 = atomicAdd(&cur[d4.y >> BKTL2], 1);
            int p2 = atomicAdd(&cur[d4.z >> BKTL2], 1);
            int p3 = atomicAdd(&cur[d4.w >> BKTL2], 1);
            packed[p0] = (s4.x << BKTL2) | (d4.x & (BKT - 1));
            packed[p1] = (s4.y << BKTL2) | (d4.y & (BKT - 1));
            packed[p2] = (s4.z << BKTL2) | (d4.z & (BKT - 1));
            packed[p3] = (s4.w << BKTL2) | (d4.w & (BKT - 1));
        } else {
            for (int j = i; j < e && j < i + 4; ++j) {
                int s = ei[j], d = ei[e + j];
                int p = atomicAdd(&cur[d >> BKTL2], 1);
                packed[p] = (s << BKTL2) | (d & (BKT - 1));
            }
        }
    }
}

// ---- per bucket (512 threads): LDS degree+scan -> rowptr/dinv; place col ----
__global__ void k_place2(const int* __restrict__ packed, const int* __restrict__ bstart,
                         int* __restrict__ col, int* __restrict__ rp,
                         float* __restrict__ dinv, int n) {
    __shared__ int deg[BKT];
    __shared__ int sc[BKT];
    __shared__ int cur[BKT];
    int t = threadIdx.x;
    deg[t] = 0;
    __syncthreads();
    int start = bstart[blockIdx.x];
    int end = bstart[blockIdx.x + 1];
    for (int i = start + t; i < end; i += BKT)
        atomicAdd(&deg[packed[i] & (BKT - 1)], 1);
    __syncthreads();
    int d0 = deg[t];
    sc[t] = d0;
    __syncthreads();
    int val = d0;
    for (int off = 1; off < BKT; off <<= 1) {
        int other = (t >= off) ? sc[t - off] : 0;
        __syncthreads();
        val += other;
        sc[t] = val;
        __syncthreads();
    }
    int node = blockIdx.x * BKT + t;
    int ex = start + val - d0;   // bucket start + exclusive prefix
    if (node < n) {
        rp[node] = ex;
        dinv[node] = rsqrtf((float)d0 + 1.0f);
    }
    cur[t] = ex;
    __syncthreads();
    for (int i = start + t; i < end; i += BKT) {
        int u = packed[i];
        int p = atomicAdd(&cur[u & (BKT - 1)], 1);
        col[p] = u >> BKTL2;
    }
}

// ---- h0 = x @ W1 (K=3), fp16 out, two planes ----
__global__ void k_xw1(const float* __restrict__ x, const float* __restrict__ W1,
                      _Float16* __restrict__ p0, _Float16* __restrict__ p1, int n) {
    int i = blockIdx.x * blockDim.x + threadIdx.x;
    if (i >= n * F) return;
    int node = i >> 5, f = i & (F - 1);
    float x0 = x[node * 3 + 0], x1 = x[node * 3 + 1], x2 = x[node * 3 + 2];
    float v = x0 * W1[f] + x1 * W1[F + f] + x2 * W1[2 * F + f];
    _Float16* plane = (f < 16) ? p0 : p1;
    plane[node * 16 + (f & 15)] = (_Float16)v;
}

// ---- g = h @ W2 (32x32), fp16 planes in/out, fp32 accumulate ----
__global__ void k_gemm2(const _Float16* __restrict__ h0, const _Float16* __restrict__ h1,
                        const float* __restrict__ W2,
                        _Float16* __restrict__ g0, _Float16* __restrict__ g1, int n) {
    int i = blockIdx.x * blockDim.x + threadIdx.x;
    if (i >= n * F) return;
    int node = i >> 5, f = i & (F - 1);
    const _Float16* r0 = h0 + (size_t)node * 16;
    const _Float16* r1 = h1 + (size_t)node * 16;
    float acc = 0.0f;
#pragma unroll
    for (int k = 0; k < 16; ++k) acc += (float)r0[k] * W2[k * F + f];
#pragma unroll
    for (int k = 0; k < 16; ++k) acc += (float)r1[k] * W2[(k + 16) * F + f];
    _Float16* plane = (f < 16) ? g0 : g1;
    plane[node * 16 + (f & 15)] = (_Float16)acc;
}

// ---- fused gather conv + bias + relu + pool over ONE feature plane ----
// 2 threads/node (8 feats each); 8-deep unrolled edge loop.
// plane: N x 16 fp16 (32B rows, L2-resident). fh selects feature half.
__global__ void k_gather(const _Float16* __restrict__ plane, const int* __restrict__ rp,
                         const int* __restrict__ col, const float* __restrict__ dinv,
                         const float* __restrict__ bias, const int* __restrict__ batch,
                         _Float16* __restrict__ outPlane,
                         float* __restrict__ psum, float* __restrict__ pmax,
                         float* __restrict__ cnt, int n, int ne, int fh,
                         int store, int do_cnt) {
    int t = blockIdx.x * blockDim.x + threadIdx.x;
    int node = t >> 1, q = t & 1;
    if (node >= n) return;
    int start = rp[node];
    int end = (node + 1 < n) ? rp[node + 1] : ne;
    float dv = dinv[node];

    half8 hv = *reinterpret_cast<const half8*>(plane + (size_t)node * 16 + q * 8);
    float dvv = dv * dv;
    float acc[8];
#pragma unroll
    for (int j = 0; j < 8; ++j) acc[j] = (float)hv[j] * dvv;

    int e = start;
    for (; e + 8 <= end; e += 8) {
        int s[8];
#pragma unroll
        for (int u = 0; u < 8; ++u) s[u] = col[e + u];
        half8 v[8];
#pragma unroll
        for (int u = 0; u < 8; ++u)
            v[u] = *reinterpret_cast<const half8*>(plane + (size_t)s[u] * 16 + q * 8);
        float w[8];
#pragma unroll
        for (int u = 0; u < 8; ++u) w[u] = dinv[s[u]] * dv;
#pragma unroll
        for (int u = 0; u < 8; ++u)
#pragma unroll
            for (int j = 0; j < 8; ++j) acc[j] += (float)v[u][j] * w[u];
    }
    for (; e < end; ++e) {
        int s = col[e];
        float wv = dinv[s] * dv;
        half8 v = *reinterpret_cast<const half8*>(plane + (size_t)s * 16 + q * 8);
#pragma unroll
        for (int j = 0; j < 8; ++j) acc[j] += (float)v[j] * wv;
    }

    float vv[8];
#pragma unroll
    for (int j = 0; j < 8; ++j)
        vv[j] = fmaxf(acc[j] + bias[fh * 16 + q * 8 + j], 0.0f);
    if (store) {
        half8 o;
#pragma unroll
        for (int j = 0; j < 8; ++j) o[j] = (_Float16)vv[j];
        *reinterpret_cast<half8*>(outPlane + (size_t)node * 16 + q * 8) = o;
    }

    int b = batch[node];
    int lane = threadIdx.x & 63;
    int bFirst = __shfl(b, 0);
    int bLast  = __shfl(b, 63);
    if (bFirst == bLast) {
        // all 32 nodes of this wave in one graph: stride-2 tree reduce
        float sv[8], mv[8];
#pragma unroll
        for (int j = 0; j < 8; ++j) { sv[j] = vv[j]; mv[j] = vv[j]; }
        for (int off = 2; off < 64; off <<= 1) {
#pragma unroll
            for (int j = 0; j < 8; ++j) {
                sv[j] += __shfl_down(sv[j], off);
                mv[j] = fmaxf(mv[j], __shfl_down(mv[j], off));
            }
        }
        if (lane < 2) {
            float* ps = psum + b * F + fh * 16 + lane * 8;
            int* pm = reinterpret_cast<int*>(pmax + b * F + fh * 16 + lane * 8);
#pragma unroll
            for (int j = 0; j < 8; ++j) {
                atomicAdd(ps + j, sv[j]);
                atomicMax(pm + j, __float_as_int(mv[j]));  // vv >= 0
            }
            if (do_cnt && lane == 0) atomicAdd(&cnt[b], 32.0f);
        }
    } else {
        float* ps = psum + b * F + fh * 16 + q * 8;
        int* pm = reinterpret_cast<int*>(pmax + b * F + fh * 16 + q * 8);
#pragma unroll
        for (int j = 0; j < 8; ++j) {
            atomicAdd(ps + j, vv[j]);
            atomicMax(pm + j, __float_as_int(vv[j]));
        }
        if (do_cnt && q == 0) atomicAdd(&cnt[b], 1.0f);
    }
}

// ---- fused MLP head: one block per graph (64 threads) ----
__global__ void k_mlp(const float* __restrict__ sum1, const float* __restrict__ max1,
                      const float* __restrict__ sum2, const float* __restrict__ max2,
                      const float* __restrict__ cnt,
                      const float* __restrict__ LW1, const float* __restrict__ Lb1,
                      const float* __restrict__ LW2, const float* __restrict__ Lb2,
                      float* __restrict__ out, int outd) {
    __shared__ float zs[POOLD];
    int b = blockIdx.x, j = threadIdx.x;  // blockDim.x == 64
    float invc = 1.0f / fmaxf(cnt[b], 1.0f);
    float acc = Lb1[j];
#pragma unroll
    for (int i = 0; i < POOLD; ++i) {
        float s;
        if (i < F) s = max1[b * F + i] + max2[b * F + i];
        else       s = (sum1[b * F + i - F] + sum2[b * F + i - F]) * invc;
        acc += s * LW1[i * POOLD + j];
    }
    zs[j] = fmaxf(acc, 0.0f);
    __syncthreads();
    if (j < outd) {
        float a2 = Lb2[j];
#pragma unroll
        for (int jj = 0; jj < POOLD; ++jj) a2 += zs[jj] * LW2[jj * outd + j];
        out[b * outd + j] = a2;
    }
}

extern "C" void kernel_launch(void* const* d_in, const int* in_sizes, int n_in,
                              void* d_out, int out_size, void* d_ws, size_t ws_size,
                              hipStream_t stream) {
    const float* x    = (const float*)d_in[0];
    const int*   ei   = (const int*)d_in[1];
    const int*   batch= (const int*)d_in[2];
    const float* W1   = (const float*)d_in[3];
    const float* b1   = (const float*)d_in[4];
    const float* W2   = (const float*)d_in[5];
    const float* b2   = (const float*)d_in[6];
    const float* LW1  = (const float*)d_in[7];
    const float* Lb1  = (const float*)d_in[8];
    const float* LW2  = (const float*)d_in[9];
    const float* Lb2  = (const float*)d_in[10];
    float* out = (float*)d_out;

    const int N = in_sizes[0] / 3;
    const int E = in_sizes[1] / 2;
    const int OUTD = in_sizes[10];
    const int B = out_size / OUTD;
    const int poolsz = 4 * B * F + B;
    const int NBUCK = (N + BKT - 1) / BKT;      // <= MAXBUCK
    const int NBLK = (E + EPB - 1) / EPB;

    // ---- workspace layout ----
    char* p = (char*)d_ws;
    float* pools= (float*)p;          p += (size_t)poolsz * 4;
    int* bcnt   = (int*)p;            p += (size_t)NBUCK * NBLK * 4;
    int* tot    = (int*)p;            p += (size_t)MAXBUCK * 4;
    int* bstart = (int*)p;            p += (size_t)(NBUCK + 1) * 4;
    int* rowptr = (int*)p;            p += (size_t)N * 4;
    int* col    = (int*)p;            p += (size_t)E * 4;
    float* dinv = (float*)p;          p += (size_t)N * 4;
    _Float16* b0p0 = (_Float16*)p;    p += (size_t)N * 16 * 2;   // buf0 plane0
    _Float16* b0p1 = (_Float16*)p;    p += (size_t)N * 16 * 2;   // buf0 plane1
    _Float16* b1p0 = (_Float16*)p;    p += (size_t)N * 16 * 2;   // buf1 plane0
    _Float16* b1p1 = (_Float16*)p;    p += (size_t)N * 16 * 2;   // buf1 plane1
    int* packed = (int*)b0p0;         // aliased over the 4 planes (E*4 == N*F*4 B);
                                      // consumed by k_place2 before planes written
    float* sum1 = pools;
    float* max1 = sum1 + B * F;
    float* sum2 = max1 + B * F;
    float* max2 = sum2 + B * F;
    float* cnt  = max2 + B * F;

    const int BS = 256;
    auto g1 = [&](long long n) { return (int)((n + BS - 1) / BS); };

    // CSR build + norms (zero global atomics)
    hipMemsetAsync(pools, 0, (size_t)poolsz * 4, stream);
    k_histB<<<NBLK, BS, 0, stream>>>(ei, bcnt, E, NBUCK, NBLK);
    k_rowscan<<<NBUCK, 256, 0, stream>>>(bcnt, tot, NBLK);
    k_bscan<<<1, 256, 0, stream>>>(tot, bstart, NBUCK, E);
    k_bin<<<NBLK, BS, 0, stream>>>(ei, bstart, bcnt, packed, E, NBUCK, NBLK);
    k_place2<<<NBUCK, BKT, 0, stream>>>(packed, bstart, col, rowptr, dinv, N);

    // layer 1: h0 planes -> gather per plane -> h (buf1 planes)
    k_xw1<<<g1((long long)N * F), BS, 0, stream>>>(x, W1, b0p0, b0p1, N);
    k_gather<<<g1((long long)N * 2), BS, 0, stream>>>(b0p0, rowptr, col, dinv, b1,
                                                      batch, b1p0, sum1, max1, cnt,
                                                      N, E, 0, /*store=*/1, /*cnt=*/1);
    k_gather<<<g1((long long)N * 2), BS, 0, stream>>>(b0p1, rowptr, col, dinv, b1,
                                                      batch, b1p1, sum1, max1, cnt,
                                                      N, E, 1, /*store=*/1, /*cnt=*/0);
    // layer 2
    k_gemm2<<<g1((long long)N * F), BS, 0, stream>>>(b1p0, b1p1, W2, b0p0, b0p1, N);
    k_gather<<<g1((long long)N * 2), BS, 0, stream>>>(b0p0, rowptr, col, dinv, b2,
                                                      batch, b1p0, sum2, max2, cnt,
                                                      N, E, 0, /*store=*/0, /*cnt=*/0);
    k_gather<<<g1((long long)N * 2), BS, 0, stream>>>(b0p1, rowptr, col, dinv, b2,
                                                      batch, b1p1, sum2, max2, cnt,
                                                      N, E, 1, /*store=*/0, /*cnt=*/0);

    // MLP head
    k_mlp<<<B, 64, 0, stream>>>(sum1, max1, sum2, max2, cnt,
                                LW1, Lb1, LW2, Lb2, out, OUTD);
}

// Round 10
// 369.095 us; speedup vs baseline: 1.0561x; 1.0561x over previous
//
#include <hip/hip_runtime.h>
#include <hip/hip_fp16.h>

// Topology encoder: 2-layer GCN (N=100k nodes, E=3.2M edges) + max/mean pool
// over B=64 graphs + 2-layer MLP. fp32 in/out; node features stored fp16 in
// TWO PLANES of N x 16 (3.2 MB each -> L2-resident per XCD during gathers).
//
// CSR-by-dst built per call with ZERO global atomics (histB/rowscan/bscan/
// bin/place2 as before). Each GCN layer = ONE gather kernel processing both
// planes concurrently: plane chosen by blockIdx&7 (XCD round-robin pinning,
// planes live in disjoint XCD L2 halves); 4 threads per (node,plane) =
// 2 feature-halves x 2 edge-parities (halves the dependent-load chain).

#define F 32
#define POOLD 64
#define BKT 512           // nodes per bucket (log2 = 9); place2 blockDim == BKT
#define BKTL2 9
#define EPB 8192          // edges per k_histB/k_bin block
#define MAXBUCK 256       // supports N <= 131072

typedef __attribute__((ext_vector_type(8))) _Float16 half8;

// ---- per-block LDS bucket histogram; direct store to bcnt[b][blk] ----
__global__ void k_histB(const int* __restrict__ ei, int* __restrict__ bcnt,
                        int e, int nbuck, int nblk) {
    __shared__ int h[MAXBUCK];
    for (int b = threadIdx.x; b < nbuck; b += 256) h[b] = 0;
    __syncthreads();
    int base = blockIdx.x * EPB;
#pragma unroll
    for (int k = 0; k < EPB / 1024; ++k) {
        int i = base + (k * 256 + threadIdx.x) * 4;
        if (i + 4 <= e) {
            int4 d4 = *reinterpret_cast<const int4*>(ei + e + i);
            atomicAdd(&h[d4.x >> BKTL2], 1);
            atomicAdd(&h[d4.y >> BKTL2], 1);
            atomicAdd(&h[d4.z >> BKTL2], 1);
            atomicAdd(&h[d4.w >> BKTL2], 1);
        } else {
            for (int j = i; j < e && j < i + 4; ++j)
                atomicAdd(&h[ei[e + j] >> BKTL2], 1);
        }
    }
    __syncthreads();
    for (int b = threadIdx.x; b < nbuck; b += 256)
        bcnt[b * nblk + blockIdx.x] = h[b];
}

// ---- per bucket: exclusive scan of bcnt row (in place) + row total ----
__global__ void k_rowscan(int* __restrict__ bcnt, int* __restrict__ tot, int nblk) {
    __shared__ int lds[256];
    int* row = bcnt + (size_t)blockIdx.x * nblk;
    int t = threadIdx.x;
    int running = 0;
    for (int chunk = 0; chunk < nblk; chunk += 256) {
        int idx = chunk + t;
        int v = (idx < nblk) ? row[idx] : 0;
        lds[t] = v;
        __syncthreads();
        int val = v;
        for (int off = 1; off < 256; off <<= 1) {
            int other = (t >= off) ? lds[t - off] : 0;
            __syncthreads();
            val += other;
            lds[t] = val;
            __syncthreads();
        }
        if (idx < nblk) row[idx] = running + val - v;  // exclusive
        running += lds[255];
        __syncthreads();
    }
    if (t == 0) tot[blockIdx.x] = running;
}

// ---- single block: scan bucket totals -> bstart (nbuck <= 256) ----
__global__ void k_bscan(const int* __restrict__ tot, int* __restrict__ bstart,
                        int nbuck, int e) {
    __shared__ int lds[256];
    int t = threadIdx.x;
    int v = (t < nbuck) ? tot[t] : 0;
    lds[t] = v;
    __syncthreads();
    int val = v;
    for (int off = 1; off < 256; off <<= 1) {
        int other = (t >= off) ? lds[t - off] : 0;
        __syncthreads();
        val += other;
        lds[t] = val;
        __syncthreads();
    }
    if (t < nbuck) bstart[t] = val - v;  // exclusive
    if (t == 0) bstart[nbuck] = e;
}

// ---- partition edges into private per-(bucket,block) runs; LDS cursors ----
__global__ void k_bin(const int* __restrict__ ei, const int* __restrict__ bstart,
                      const int* __restrict__ bcnt, int* __restrict__ packed,
                      int e, int nbuck, int nblk) {
    __shared__ int cur[MAXBUCK];
    for (int b = threadIdx.x; b < nbuck; b += 256)
        cur[b] = bstart[b] + bcnt[b * nblk + blockIdx.x];
    __syncthreads();
    int base = blockIdx.x * EPB;
#pragma unroll
    for (int k = 0; k < EPB / 1024; ++k) {
        int i = base + (k * 256 + threadIdx.x) * 4;
        if (i + 4 <= e) {
            int4 s4 = *reinterpret_cast<const int4*>(ei + i);
            int4 d4 = *reinterpret_cast<const int4*>(ei + e + i);
            int p0 = atomicAdd(&cur[d4.x >> BKTL2], 1);
            int p1 = atomicAdd(&cur[d4.y >> BKTL2], 1);
            int p2 = atomicAdd(&cur[d4.z >> BKTL2], 1);
            int p3 = atomicAdd(&cur[d4.w >> BKTL2], 1);
            packed[p0] = (s4.x << BKTL2) | (d4.x & (BKT - 1));
            packed[p1] = (s4.y << BKTL2) | (d4.y & (BKT - 1));
            packed[p2] = (s4.z << BKTL2) | (d4.z & (BKT - 1));
            packed[p3] = (s4.w << BKTL2) | (d4.w & (BKT - 1));
        } else {
            for (int j = i; j < e && j < i + 4; ++j) {
                int s = ei[j], d = ei[e + j];
                int p = atomicAdd(&cur[d >> BKTL2], 1);
                packed[p] = (s << BKTL2) | (d & (BKT - 1));
            }
        }
    }
}

// ---- per bucket (512 threads): LDS degree+scan -> rowptr/dinv; place col ----
__global__ void k_place2(const int* __restrict__ packed, const int* __restrict__ bstart,
                         int* __restrict__ col, int* __restrict__ rp,
                         float* __restrict__ dinv, int n) {
    __shared__ int deg[BKT];
    __shared__ int sc[BKT];
    __shared__ int cur[BKT];
    int t = threadIdx.x;
    deg[t] = 0;
    __syncthreads();
    int start = bstart[blockIdx.x];
    int end = bstart[blockIdx.x + 1];
    for (int i = start + t; i < end; i += BKT)
        atomicAdd(&deg[packed[i] & (BKT - 1)], 1);
    __syncthreads();
    int d0 = deg[t];
    sc[t] = d0;
    __syncthreads();
    int val = d0;
    for (int off = 1; off < BKT; off <<= 1) {
        int other = (t >= off) ? sc[t - off] : 0;
        __syncthreads();
        val += other;
        sc[t] = val;
        __syncthreads();
    }
    int node = blockIdx.x * BKT + t;
    int ex = start + val - d0;   // bucket start + exclusive prefix
    if (node < n) {
        rp[node] = ex;
        dinv[node] = rsqrtf((float)d0 + 1.0f);
    }
    cur[t] = ex;
    __syncthreads();
    for (int i = start + t; i < end; i += BKT) {
        int u = packed[i];
        int p = atomicAdd(&cur[u & (BKT - 1)], 1);
        col[p] = u >> BKTL2;
    }
}

// ---- h0 = x @ W1 (K=3), fp16 out, two planes ----
__global__ void k_xw1(const float* __restrict__ x, const float* __restrict__ W1,
                      _Float16* __restrict__ p0, _Float16* __restrict__ p1, int n) {
    int i = blockIdx.x * blockDim.x + threadIdx.x;
    if (i >= n * F) return;
    int node = i >> 5, f = i & (F - 1);
    float x0 = x[node * 3 + 0], x1 = x[node * 3 + 1], x2 = x[node * 3 + 2];
    float v = x0 * W1[f] + x1 * W1[F + f] + x2 * W1[2 * F + f];
    _Float16* plane = (f < 16) ? p0 : p1;
    plane[node * 16 + (f & 15)] = (_Float16)v;
}

// ---- g = h @ W2 (32x32), fp16 planes in/out, fp32 accumulate ----
__global__ void k_gemm2(const _Float16* __restrict__ h0, const _Float16* __restrict__ h1,
                        const float* __restrict__ W2,
                        _Float16* __restrict__ g0, _Float16* __restrict__ g1, int n) {
    int i = blockIdx.x * blockDim.x + threadIdx.x;
    if (i >= n * F) return;
    int node = i >> 5, f = i & (F - 1);
    const _Float16* r0 = h0 + (size_t)node * 16;
    const _Float16* r1 = h1 + (size_t)node * 16;
    float acc = 0.0f;
#pragma unroll
    for (int k = 0; k < 16; ++k) acc += (float)r0[k] * W2[k * F + f];
#pragma unroll
    for (int k = 0; k < 16; ++k) acc += (float)r1[k] * W2[(k + 16) * F + f];
    _Float16* plane = (f < 16) ? g0 : g1;
    plane[node * 16 + (f & 15)] = (_Float16)acc;
}

// ---- fused gather conv + bias + relu + pool, BOTH planes in one launch ----
// blockIdx&7: sub 0-3 -> plane 0, sub 4-7 -> plane 1 (XCD round-robin pins
// each plane to half the XCDs -> 3.2MB/L2). 64 nodes/block; thread t:
// nodeLocal=t>>2, q=(t>>1)&1 (feat half), r=t&1 (edge parity).
// NOTE: assumes N%64 is a multiple of 16 so waves are fully valid or empty.
__global__ void k_gather2(const _Float16* __restrict__ pl0, const _Float16* __restrict__ pl1,
                          const int* __restrict__ rp, const int* __restrict__ col,
                          const float* __restrict__ dinv, const float* __restrict__ bias,
                          const int* __restrict__ batch,
                          _Float16* __restrict__ out0, _Float16* __restrict__ out1,
                          float* __restrict__ psum, float* __restrict__ pmax,
                          float* __restrict__ cnt, int n, int ne, int nPB,
                          int store, int do_cnt) {
    int grp = blockIdx.x >> 3, sub = blockIdx.x & 7;
    int plane = sub >> 2;
    int lb = grp * 4 + (sub & 3);
    if (lb >= nPB) return;
    int t = threadIdx.x;
    int node = (lb << 6) + (t >> 2);
    int q = (t >> 1) & 1, r = t & 1;
    if (node >= n) return;

    const _Float16* hin = plane ? pl1 : pl0;
    int start = rp[node];
    int end = (node + 1 < n) ? rp[node + 1] : ne;
    float dv = dinv[node];

    float acc[8];
    {   // self-loop (r==0 contributes; r==1 starts at zero)
        half8 hv = *reinterpret_cast<const half8*>(hin + (size_t)node * 16 + q * 8);
        float dvv = (r == 0) ? dv * dv : 0.0f;
#pragma unroll
        for (int j = 0; j < 8; ++j) acc[j] = (float)hv[j] * dvv;
    }

    // edges of parity r: start+r, start+r+2, ... ; 4-deep unrolled
    int e = start + r;
    for (; e + 6 < end; e += 8) {
        int s0 = col[e], s1 = col[e + 2], s2 = col[e + 4], s3 = col[e + 6];
        half8 v0 = *reinterpret_cast<const half8*>(hin + (size_t)s0 * 16 + q * 8);
        half8 v1 = *reinterpret_cast<const half8*>(hin + (size_t)s1 * 16 + q * 8);
        half8 v2 = *reinterpret_cast<const half8*>(hin + (size_t)s2 * 16 + q * 8);
        half8 v3 = *reinterpret_cast<const half8*>(hin + (size_t)s3 * 16 + q * 8);
        float w0 = dinv[s0] * dv, w1 = dinv[s1] * dv,
              w2 = dinv[s2] * dv, w3 = dinv[s3] * dv;
#pragma unroll
        for (int j = 0; j < 8; ++j)
            acc[j] += (float)v0[j] * w0 + (float)v1[j] * w1 +
                      (float)v2[j] * w2 + (float)v3[j] * w3;
    }
    for (; e < end; e += 2) {
        int s = col[e];
        float wv = dinv[s] * dv;
        half8 v = *reinterpret_cast<const half8*>(hin + (size_t)s * 16 + q * 8);
#pragma unroll
        for (int j = 0; j < 8; ++j) acc[j] += (float)v[j] * wv;
    }

    // combine edge-parity partners (lane ^ 1)
#pragma unroll
    for (int j = 0; j < 8; ++j) acc[j] += __shfl_xor(acc[j], 1);

    float vv[8];
#pragma unroll
    for (int j = 0; j < 8; ++j)
        vv[j] = fmaxf(acc[j] + bias[plane * 16 + q * 8 + j], 0.0f);

    if (store && r == 0) {
        _Float16* hout = plane ? out1 : out0;
        half8 o;
#pragma unroll
        for (int j = 0; j < 8; ++j) o[j] = (_Float16)vv[j];
        *reinterpret_cast<half8*>(hout + (size_t)node * 16 + q * 8) = o;
    }

    int b = batch[node];
    int lane = t & 63;
    int bFirst = __shfl(b, 0);
    int bLast  = __shfl(b, 63);
    if (bFirst == bLast) {
        // 16 nodes per wave, stride-4 tree reduce (q,r preserved)
        float sv[8], mv[8];
#pragma unroll
        for (int j = 0; j < 8; ++j) { sv[j] = vv[j]; mv[j] = vv[j]; }
        for (int off = 4; off < 64; off <<= 1) {
#pragma unroll
            for (int j = 0; j < 8; ++j) {
                sv[j] += __shfl_down(sv[j], off);
                mv[j] = fmaxf(mv[j], __shfl_down(mv[j], off));
            }
        }
        if (lane < 4 && r == 0) {   // lanes 0 (q0) and 2 (q1)
            float* ps = psum + b * F + plane * 16 + q * 8;
            int* pm = reinterpret_cast<int*>(pmax + b * F + plane * 16 + q * 8);
#pragma unroll
            for (int j = 0; j < 8; ++j) {
                atomicAdd(ps + j, sv[j]);
                atomicMax(pm + j, __float_as_int(mv[j]));  // vv >= 0
            }
            if (do_cnt && plane == 0 && lane == 0) atomicAdd(&cnt[b], 16.0f);
        }
    } else if (r == 0) {
        float* ps = psum + b * F + plane * 16 + q * 8;
        int* pm = reinterpret_cast<int*>(pmax + b * F + plane * 16 + q * 8);
#pragma unroll
        for (int j = 0; j < 8; ++j) {
            atomicAdd(ps + j, vv[j]);
            atomicMax(pm + j, __float_as_int(vv[j]));
        }
        if (do_cnt && plane == 0 && q == 0) atomicAdd(&cnt[b], 1.0f);
    }
}

// ---- fused MLP head: one block per graph (64 threads) ----
__global__ void k_mlp(const float* __restrict__ sum1, const float* __restrict__ max1,
                      const float* __restrict__ sum2, const float* __restrict__ max2,
                      const float* __restrict__ cnt,
                      const float* __restrict__ LW1, const float* __restrict__ Lb1,
                      const float* __restrict__ LW2, const float* __restrict__ Lb2,
                      float* __restrict__ out, int outd) {
    __shared__ float zs[POOLD];
    int b = blockIdx.x, j = threadIdx.x;  // blockDim.x == 64
    float invc = 1.0f / fmaxf(cnt[b], 1.0f);
    float acc = Lb1[j];
#pragma unroll
    for (int i = 0; i < POOLD; ++i) {
        float s;
        if (i < F) s = max1[b * F + i] + max2[b * F + i];
        else       s = (sum1[b * F + i - F] + sum2[b * F + i - F]) * invc;
        acc += s * LW1[i * POOLD + j];
    }
    zs[j] = fmaxf(acc, 0.0f);
    __syncthreads();
    if (j < outd) {
        float a2 = Lb2[j];
#pragma unroll
        for (int jj = 0; jj < POOLD; ++jj) a2 += zs[jj] * LW2[jj * outd + j];
        out[b * outd + j] = a2;
    }
}

extern "C" void kernel_launch(void* const* d_in, const int* in_sizes, int n_in,
                              void* d_out, int out_size, void* d_ws, size_t ws_size,
                              hipStream_t stream) {
    const float* x    = (const float*)d_in[0];
    const int*   ei   = (const int*)d_in[1];
    const int*   batch= (const int*)d_in[2];
    const float* W1   = (const float*)d_in[3];
    const float* b1   = (const float*)d_in[4];
    const float* W2   = (const float*)d_in[5];
    const float* b2   = (const float*)d_in[6];
    const float* LW1  = (const float*)d_in[7];
    const float* Lb1  = (const float*)d_in[8];
    const float* LW2  = (const float*)d_in[9];
    const float* Lb2  = (const float*)d_in[10];
    float* out = (float*)d_out;

    const int N = in_sizes[0] / 3;
    const int E = in_sizes[1] / 2;
    const int OUTD = in_sizes[10];
    const int B = out_size / OUTD;
    const int poolsz = 4 * B * F + B;
    const int NBUCK = (N + BKT - 1) / BKT;      // <= MAXBUCK
    const int NBLK = (E + EPB - 1) / EPB;
    const int NPB = (N + 63) / 64;              // gather blocks per plane

    // ---- workspace layout ----
    char* p = (char*)d_ws;
    float* pools= (float*)p;          p += (size_t)poolsz * 4;
    int* bcnt   = (int*)p;            p += (size_t)NBUCK * NBLK * 4;
    int* tot    = (int*)p;            p += (size_t)MAXBUCK * 4;
    int* bstart = (int*)p;            p += (size_t)(NBUCK + 1) * 4;
    int* rowptr = (int*)p;            p += (size_t)N * 4;
    int* col    = (int*)p;            p += (size_t)E * 4;
    float* dinv = (float*)p;          p += (size_t)N * 4;
    _Float16* b0p0 = (_Float16*)p;    p += (size_t)N * 16 * 2;   // buf0 plane0
    _Float16* b0p1 = (_Float16*)p;    p += (size_t)N * 16 * 2;   // buf0 plane1
    _Float16* b1p0 = (_Float16*)p;    p += (size_t)N * 16 * 2;   // buf1 plane0
    _Float16* b1p1 = (_Float16*)p;    p += (size_t)N * 16 * 2;   // buf1 plane1
    int* packed = (int*)b0p0;         // aliased over the 4 planes (E*4 == N*F*4 B);
                                      // consumed by k_place2 before planes written
    float* sum1 = pools;
    float* max1 = sum1 + B * F;
    float* sum2 = max1 + B * F;
    float* max2 = sum2 + B * F;
    float* cnt  = max2 + B * F;

    const int BS = 256;
    auto g1 = [&](long long n) { return (int)((n + BS - 1) / BS); };
    const int gatherBlocks = ((NPB + 3) / 4) * 8;

    // CSR build + norms (zero global atomics)
    hipMemsetAsync(pools, 0, (size_t)poolsz * 4, stream);
    k_histB<<<NBLK, BS, 0, stream>>>(ei, bcnt, E, NBUCK, NBLK);
    k_rowscan<<<NBUCK, 256, 0, stream>>>(bcnt, tot, NBLK);
    k_bscan<<<1, 256, 0, stream>>>(tot, bstart, NBUCK, E);
    k_bin<<<NBLK, BS, 0, stream>>>(ei, bstart, bcnt, packed, E, NBUCK, NBLK);
    k_place2<<<NBUCK, BKT, 0, stream>>>(packed, bstart, col, rowptr, dinv, N);

    // layer 1: h0 planes -> single dual-plane gather -> h (buf1 planes)
    k_xw1<<<g1((long long)N * F), BS, 0, stream>>>(x, W1, b0p0, b0p1, N);
    k_gather2<<<gatherBlocks, BS, 0, stream>>>(b0p0, b0p1, rowptr, col, dinv, b1,
                                               batch, b1p0, b1p1, sum1, max1, cnt,
                                               N, E, NPB, /*store=*/1, /*cnt=*/1);
    // layer 2
    k_gemm2<<<g1((long long)N * F), BS, 0, stream>>>(b1p0, b1p1, W2, b0p0, b0p1, N);
    k_gather2<<<gatherBlocks, BS, 0, stream>>>(b0p0, b0p1, rowptr, col, dinv, b2,
                                               batch, b1p0, b1p1, sum2, max2, cnt,
                                               N, E, NPB, /*store=*/0, /*cnt=*/0);

    // MLP head
    k_mlp<<<B, 64, 0, stream>>>(sum1, max1, sum2, max2, cnt,
                                LW1, Lb1, LW2, Lb2, out, OUTD);
}